// Round 1
// baseline (384.398 us; speedup 1.0000x reference)
//
#include <hip/hip_runtime.h>
#include <stdint.h>

typedef unsigned short u16;
typedef __attribute__((ext_vector_type(8))) short short8;   // 8 bf16 = 4 VGPR
typedef __attribute__((ext_vector_type(4))) float f32x4;

#define MFMA16(a,b,c) __builtin_amdgcn_mfma_f32_16x16x32_bf16(a,b,c,0,0,0)

constexpr int B_ = 4, C_ = 512, N_ = 4096, D_ = 64;  // D_ = CQK = C/8

static __device__ __forceinline__ u16 f2bf(float f) {
    uint32_t u = __builtin_bit_cast(uint32_t, f);
    uint32_t r = (u + 0x7FFFu + ((u >> 16) & 1u)) >> 16;   // RNE
    return (u16)r;
}

// ---------------- prep: Wcat bf16 [640][512] (q rows 0-63, k 64-127, v 128-639) + biascat ----
__global__ void prep_w(const float* Wq, const float* bq, const float* Wk, const float* bk,
                       const float* Wv, const float* bv, u16* Wcat, float* biascat) {
    int idx = blockIdx.x * 256 + threadIdx.x;
    if (idx < 640 * 512) {
        int row = idx >> 9, col = idx & 511;
        float w;
        if (row < 64)        w = Wq[row * 512 + col];
        else if (row < 128)  w = Wk[(row - 64) * 512 + col];
        else                 w = Wv[(row - 128) * 512 + col];
        Wcat[idx] = f2bf(w);
    }
    if (idx < 640) {
        float bb;
        if (idx < 64)        bb = bq[idx];
        else if (idx < 128)  bb = bk[idx - 64];
        else                 bb = bv[idx - 128];
        biascat[idx] = bb;
    }
}

// ---------------- transpose x [B][C][N] f32 -> xT [B][N][C] bf16 ----------------
__global__ void transpose_x(const float* __restrict__ x, u16* __restrict__ xT) {
    __shared__ float tile[32][33];
    int n0 = blockIdx.x * 32, c0 = blockIdx.y * 32, b = blockIdx.z;
    int tx = threadIdx.x & 31, ty = threadIdx.x >> 5;       // ty 0..7
    const float* xb = x + (size_t)b * C_ * N_;
#pragma unroll
    for (int r = 0; r < 4; r++) {
        int c = ty * 4 + r;
        tile[c][tx] = xb[(size_t)(c0 + c) * N_ + n0 + tx];
    }
    __syncthreads();
    u16* xTb = xT + (size_t)b * N_ * C_;
#pragma unroll
    for (int r = 0; r < 4; r++) {
        int n = ty * 4 + r;
        xTb[(size_t)(n0 + n) * C_ + c0 + tx] = f2bf(tile[tx][n]);
    }
}

// ---------------- projection GEMM: Y[640][4096] = Wcat x X_b^T, per batch --------
// writes qT/kT [B][N][64] (transposed) and v [B][C][N]
__global__ __launch_bounds__(256) void proj_gemm(const u16* __restrict__ Wcat,
                                                 const float* __restrict__ biascat,
                                                 const u16* __restrict__ xT,
                                                 u16* __restrict__ qT, u16* __restrict__ kT,
                                                 u16* __restrict__ v) {
    int b = blockIdx.z;
    int m0 = blockIdx.y * 64;
    int wave = threadIdx.x >> 6, lane = threadIdx.x & 63;
    int n0 = blockIdx.x * 256 + wave * 64;
    int lr = lane & 15, lc = lane >> 4;
    const u16* xTb = xT + (size_t)b * N_ * C_;

    f32x4 acc[4][4] = {};   // [ma][na]
    for (int k0 = 0; k0 < 512; k0 += 32) {
        short8 aF[4], bF[4];
#pragma unroll
        for (int ma = 0; ma < 4; ma++)
            aF[ma] = *reinterpret_cast<const short8*>(&Wcat[(size_t)(m0 + ma * 16 + lr) * 512 + k0 + lc * 8]);
#pragma unroll
        for (int na = 0; na < 4; na++)
            bF[na] = *reinterpret_cast<const short8*>(&xTb[(size_t)(n0 + na * 16 + lr) * 512 + k0 + lc * 8]);
#pragma unroll
        for (int ma = 0; ma < 4; ma++)
#pragma unroll
            for (int na = 0; na < 4; na++)
                acc[ma][na] = MFMA16(aF[ma], bF[na], acc[ma][na]);
    }
    // epilogue: bias + scatter to qT/kT (n-major) or v (c-major)
#pragma unroll
    for (int ma = 0; ma < 4; ma++) {
#pragma unroll
        for (int r = 0; r < 4; r++) {
            int m = m0 + ma * 16 + lc * 4 + r;
            float bias = biascat[m];
#pragma unroll
            for (int na = 0; na < 4; na++) {
                int n = n0 + na * 16 + lr;
                u16 hv = f2bf(acc[ma][na][r] + bias);
                if (m < 64)
                    qT[((size_t)b * N_ + n) * D_ + m] = hv;
                else if (m < 128)
                    kT[((size_t)b * N_ + n) * D_ + (m - 64)] = hv;
                else
                    v[((size_t)b * C_ + (m - 128)) * (size_t)N_ + n] = hv;
            }
        }
    }
}

// ---------------- fused attention: per (b, 32-row i-tile), 8 waves ----------------
// Pass A: online row max + sumexp (scalars only). Pass B: recompute S, P -> LDS
// (XOR-swizzled), each wave accumulates its 64-c slice of O = P*V. Epilogue fuses
// out = gamma*O + x.
__global__ __launch_bounds__(512) void attn(const u16* __restrict__ qT, const u16* __restrict__ kT,
                                            const u16* __restrict__ v, const float* __restrict__ x,
                                            const float* __restrict__ gamma_p, float* __restrict__ out) {
    int b = blockIdx.y;
    int i0 = blockIdx.x * 32;
    int wave = threadIdx.x >> 6, lane = threadIdx.x & 63;
    int lr = lane & 15, lc = lane >> 4;

    __shared__ u16 P_lds[32 * 128];          // 8KB, swizzled: byte = i*256 + ((j*2)^((i&15)<<4))
    __shared__ float s_m[8][32], s_l[8][32]; // per-wave partial (m,l)

    const u16* qTb = qT + (size_t)b * N_ * D_;
    const u16* kTb = kT + (size_t)b * N_ * D_;

    // Q fragments (held all kernel): A[m=i][k=d]
    short8 qf[2][2];
#pragma unroll
    for (int mt = 0; mt < 2; mt++)
#pragma unroll
        for (int kt = 0; kt < 2; kt++)
            qf[mt][kt] = *reinterpret_cast<const short8*>(&qTb[(size_t)(i0 + mt * 16 + lr) * D_ + kt * 32 + lc * 8]);

    // ---------- Pass A: wave w owns j in [w*512, w*512+512) ----------
    float mrun[2][4], lrun[2][4];
#pragma unroll
    for (int mt = 0; mt < 2; mt++)
#pragma unroll
        for (int r = 0; r < 4; r++) { mrun[mt][r] = -1e30f; lrun[mt][r] = 0.f; }

    for (int jj = 0; jj < 32; jj++) {
        int j0 = wave * 512 + jj * 16;
        short8 kf0 = *reinterpret_cast<const short8*>(&kTb[(size_t)(j0 + lr) * D_ + lc * 8]);
        short8 kf1 = *reinterpret_cast<const short8*>(&kTb[(size_t)(j0 + lr) * D_ + 32 + lc * 8]);
#pragma unroll
        for (int mt = 0; mt < 2; mt++) {
            f32x4 s = {};
            s = MFMA16(qf[mt][0], kf0, s);
            s = MFMA16(qf[mt][1], kf1, s);
#pragma unroll
            for (int r = 0; r < 4; r++) {
                float sv = s[r];
                float nm = fmaxf(mrun[mt][r], sv);
                lrun[mt][r] = lrun[mt][r] * __expf(mrun[mt][r] - nm) + __expf(sv - nm);
                mrun[mt][r] = nm;
            }
        }
    }
    // reduce (m,l) across the 16 lanes of each col-group
#pragma unroll
    for (int mt = 0; mt < 2; mt++)
#pragma unroll
        for (int r = 0; r < 4; r++) {
            float m_ = mrun[mt][r], l_ = lrun[mt][r];
            for (int off = 1; off < 16; off <<= 1) {
                float mo = __shfl_xor(m_, off);
                float lo = __shfl_xor(l_, off);
                float nm = fmaxf(m_, mo);
                l_ = l_ * __expf(m_ - nm) + lo * __expf(mo - nm);
                m_ = nm;
            }
            mrun[mt][r] = m_; lrun[mt][r] = l_;
        }
    if (lr == 0) {
#pragma unroll
        for (int mt = 0; mt < 2; mt++)
#pragma unroll
            for (int r = 0; r < 4; r++) {
                int row = mt * 16 + lc * 4 + r;
                s_m[wave][row] = mrun[mt][r];
                s_l[wave][row] = lrun[mt][r];
            }
    }
    __syncthreads();
    // combine across 8 waves -> final (m, 1/l) per row this lane owns in D-layout
    float mfin[2][4], linv[2][4];
#pragma unroll
    for (int mt = 0; mt < 2; mt++)
#pragma unroll
        for (int r = 0; r < 4; r++) {
            int row = mt * 16 + lc * 4 + r;
            float mf = -1e30f;
#pragma unroll
            for (int w2 = 0; w2 < 8; w2++) mf = fmaxf(mf, s_m[w2][row]);
            float lf = 0.f;
#pragma unroll
            for (int w2 = 0; w2 < 8; w2++) lf += s_l[w2][row] * __expf(s_m[w2][row] - mf);
            mfin[mt][r] = mf; linv[mt][r] = 1.0f / lf;
        }

    // ---------- Pass B: j-tiles of 128 (16 per wave), P via LDS, PV per-wave c-slice ----------
    const u16* vb = v + (size_t)b * C_ * N_;
    f32x4 acc[2][4] = {};   // [mt][ct], O slice: 32 i x 64 c
    int c_base = wave * 64;

    for (int jt = 0; jt < 32; jt++) {
        int j0 = jt * 128 + wave * 16;
        short8 kf0 = *reinterpret_cast<const short8*>(&kTb[(size_t)(j0 + lr) * D_ + lc * 8]);
        short8 kf1 = *reinterpret_cast<const short8*>(&kTb[(size_t)(j0 + lr) * D_ + 32 + lc * 8]);
#pragma unroll
        for (int mt = 0; mt < 2; mt++) {
            f32x4 s = {};
            s = MFMA16(qf[mt][0], kf0, s);
            s = MFMA16(qf[mt][1], kf1, s);
#pragma unroll
            for (int r = 0; r < 4; r++) {
                float p = __expf(s[r] - mfin[mt][r]) * linv[mt][r];
                int i = mt * 16 + lc * 4 + r;
                int jloc = wave * 16 + lr;
                int byte_off = i * 256 + ((jloc * 2) ^ ((i & 15) << 4));
                *reinterpret_cast<u16*>(reinterpret_cast<char*>(P_lds) + byte_off) = f2bf(p);
            }
        }
        __syncthreads();
#pragma unroll
        for (int kt = 0; kt < 4; kt++) {
            short8 pf[2];
#pragma unroll
            for (int mt = 0; mt < 2; mt++) {
                int i = mt * 16 + lr;
                int jb = (kt * 32 + lc * 8) * 2;
                int byte_off = i * 256 + (jb ^ ((i & 15) << 4));
                pf[mt] = *reinterpret_cast<const short8*>(reinterpret_cast<char*>(P_lds) + byte_off);
            }
#pragma unroll
            for (int ct = 0; ct < 4; ct++) {
                int c = c_base + ct * 16 + lr;
                short8 vf = *reinterpret_cast<const short8*>(&vb[(size_t)c * N_ + jt * 128 + kt * 32 + lc * 8]);
#pragma unroll
                for (int mt = 0; mt < 2; mt++)
                    acc[mt][ct] = MFMA16(pf[mt], vf, acc[mt][ct]);
            }
        }
        __syncthreads();
    }

    // ---------- epilogue: out = gamma*O + x (float4 along i) ----------
    float g = gamma_p[0];
    const float* xb = x + (size_t)b * C_ * N_;
    float* ob = out + (size_t)b * C_ * N_;
#pragma unroll
    for (int mt = 0; mt < 2; mt++)
#pragma unroll
        for (int ct = 0; ct < 4; ct++) {
            int c = c_base + ct * 16 + lr;
            size_t off = (size_t)c * N_ + i0 + mt * 16 + lc * 4;
            float4 xv = *reinterpret_cast<const float4*>(&xb[off]);
            float4 ov;
            ov.x = g * acc[mt][ct][0] + xv.x;
            ov.y = g * acc[mt][ct][1] + xv.y;
            ov.z = g * acc[mt][ct][2] + xv.z;
            ov.w = g * acc[mt][ct][3] + xv.w;
            *reinterpret_cast<float4*>(&ob[off]) = ov;
        }
}

extern "C" void kernel_launch(void* const* d_in, const int* in_sizes, int n_in,
                              void* d_out, int out_size, void* d_ws, size_t ws_size,
                              hipStream_t stream) {
    const float* x     = (const float*)d_in[0];
    const float* Wq    = (const float*)d_in[1];
    const float* bq    = (const float*)d_in[2];
    const float* Wk    = (const float*)d_in[3];
    const float* bk    = (const float*)d_in[4];
    const float* Wv    = (const float*)d_in[5];
    const float* bv    = (const float*)d_in[6];
    const float* gamma = (const float*)d_in[7];
    float* out = (float*)d_out;

    char* ws = (char*)d_ws;
    // layout (bytes): xT 16MB | Wcat 640KB | biascat 2.5KB | qT 2MB | kT 2MB | v 16MB  = ~38.4MB
    u16*   xT      = (u16*)ws;
    u16*   Wcat    = (u16*)(ws + (size_t)16777216);
    float* biascat = (float*)(ws + (size_t)16777216 + 655360);
    u16*   qT      = (u16*)(ws + (size_t)16777216 + 655360 + 4096);
    u16*   kT      = qT + (size_t)B_ * N_ * D_;
    u16*   v       = kT + (size_t)B_ * N_ * D_;

    prep_w<<<1280, 256, 0, stream>>>(Wq, bq, Wk, bk, Wv, bv, Wcat, biascat);
    transpose_x<<<dim3(N_ / 32, C_ / 32, B_), 256, 0, stream>>>(x, xT);
    proj_gemm<<<dim3(N_ / 256, 640 / 64, B_), 256, 0, stream>>>(Wcat, biascat, xT, qT, kT, v);
    attn<<<dim3(N_ / 32, B_), 512, 0, stream>>>(qT, kT, v, x, gamma, out);
}

// Round 2
// 235.329 us; speedup vs baseline: 1.6334x; 1.6334x over previous
//
#include <hip/hip_runtime.h>
#include <stdint.h>

typedef unsigned short u16;
typedef __attribute__((ext_vector_type(8))) short short8;   // 8 bf16 = 4 VGPR
typedef __attribute__((ext_vector_type(4))) short s16x4;    // 4 bf16 = 2 VGPR
typedef __attribute__((ext_vector_type(4))) float f32x4;

#define MFMA16(a,b,c) __builtin_amdgcn_mfma_f32_16x16x32_bf16(a,b,c,0,0,0)

constexpr int B_ = 4, C_ = 512, N_ = 4096, D_ = 64;  // D_ = CQK = C/8

static __device__ __forceinline__ u16 f2bf(float f) {
    uint32_t u = __builtin_bit_cast(uint32_t, f);
    uint32_t r = (u + 0x7FFFu + ((u >> 16) & 1u)) >> 16;   // RNE
    return (u16)r;
}

// ---------------- prep: Wcat bf16 [640][512] (q rows 0-63, k 64-127, v 128-639) + biascat ----
__global__ void prep_w(const float* Wq, const float* bq, const float* Wk, const float* bk,
                       const float* Wv, const float* bv, u16* Wcat, float* biascat) {
    int idx = blockIdx.x * 256 + threadIdx.x;
    if (idx < 640 * 512) {
        int row = idx >> 9, col = idx & 511;
        float w;
        if (row < 64)        w = Wq[row * 512 + col];
        else if (row < 128)  w = Wk[(row - 64) * 512 + col];
        else                 w = Wv[(row - 128) * 512 + col];
        Wcat[idx] = f2bf(w);
    }
    if (idx < 640) {
        float bb;
        if (idx < 64)        bb = bq[idx];
        else if (idx < 128)  bb = bk[idx - 64];
        else                 bb = bv[idx - 128];
        biascat[idx] = bb;
    }
}

// ---------------- transpose x [B][C][N] f32 -> xT [B][N][C] bf16 ----------------
__global__ void transpose_x(const float* __restrict__ x, u16* __restrict__ xT) {
    __shared__ float tile[32][33];
    int n0 = blockIdx.x * 32, c0 = blockIdx.y * 32, b = blockIdx.z;
    int tx = threadIdx.x & 31, ty = threadIdx.x >> 5;       // ty 0..7
    const float* xb = x + (size_t)b * C_ * N_;
#pragma unroll
    for (int r = 0; r < 4; r++) {
        int c = ty * 4 + r;
        tile[c][tx] = xb[(size_t)(c0 + c) * N_ + n0 + tx];
    }
    __syncthreads();
    u16* xTb = xT + (size_t)b * N_ * C_;
#pragma unroll
    for (int r = 0; r < 4; r++) {
        int n = ty * 4 + r;
        xTb[(size_t)(n0 + n) * C_ + c0 + tx] = f2bf(tile[tx][n]);
    }
}

// ---------------- projection GEMM: Y[640][4096] = Wcat x X_b^T, per batch --------
// writes qT/kT [B][N][64] (transposed) and v [B][C][N]
__global__ __launch_bounds__(256) void proj_gemm(const u16* __restrict__ Wcat,
                                                 const float* __restrict__ biascat,
                                                 const u16* __restrict__ xT,
                                                 u16* __restrict__ qT, u16* __restrict__ kT,
                                                 u16* __restrict__ v) {
    int b = blockIdx.z;
    int m0 = blockIdx.y * 64;
    int wave = threadIdx.x >> 6, lane = threadIdx.x & 63;
    int n0 = blockIdx.x * 256 + wave * 64;
    int lr = lane & 15, lc = lane >> 4;
    const u16* xTb = xT + (size_t)b * N_ * C_;

    f32x4 acc[4][4] = {};   // [ma][na]
    for (int k0 = 0; k0 < 512; k0 += 32) {
        short8 aF[4], bF[4];
#pragma unroll
        for (int ma = 0; ma < 4; ma++)
            aF[ma] = *reinterpret_cast<const short8*>(&Wcat[(size_t)(m0 + ma * 16 + lr) * 512 + k0 + lc * 8]);
#pragma unroll
        for (int na = 0; na < 4; na++)
            bF[na] = *reinterpret_cast<const short8*>(&xTb[(size_t)(n0 + na * 16 + lr) * 512 + k0 + lc * 8]);
#pragma unroll
        for (int ma = 0; ma < 4; ma++)
#pragma unroll
            for (int na = 0; na < 4; na++)
                acc[ma][na] = MFMA16(aF[ma], bF[na], acc[ma][na]);
    }
#pragma unroll
    for (int ma = 0; ma < 4; ma++) {
#pragma unroll
        for (int r = 0; r < 4; r++) {
            int m = m0 + ma * 16 + lc * 4 + r;
            float bias = biascat[m];
#pragma unroll
            for (int na = 0; na < 4; na++) {
                int n = n0 + na * 16 + lr;
                u16 hv = f2bf(acc[ma][na][r] + bias);
                if (m < 64)
                    qT[((size_t)b * N_ + n) * D_ + m] = hv;
                else if (m < 128)
                    kT[((size_t)b * N_ + n) * D_ + (m - 64)] = hv;
                else
                    v[((size_t)b * C_ + (m - 128)) * (size_t)N_ + n] = hv;
            }
        }
    }
}

// ---------------- fused attention, one pass, no max-subtraction ----------------
// Block: 64 i-rows (BM=64); 8 waves; wave w owns c-slice [w*64, w*64+64) and ALL 64 i.
// Per j-tile of 128: wave w computes S^T for its 16-j slice via SWAPPED mfma(K,Q)
// (lane holds 4 consecutive j for one i -> ds_write_b64 P stores), P (=exp(S),
// unnormalized) goes to a double-buffered XOR-swizzled LDS tile; then PV accumulates.
// l = sum_j exp(S) accumulated per-lane, reduced at the end; epilogue divides,
// applies gamma and residual. XCD swizzle: 2 XCDs per batch so V[b] (4MB) lives in L2.
__global__ __launch_bounds__(512) void attn(const u16* __restrict__ qT, const u16* __restrict__ kT,
                                            const u16* __restrict__ v, const float* __restrict__ x,
                                            const float* __restrict__ gamma_p, float* __restrict__ out) {
    // ---- XCD-aware decode: xcd = wgid % 8 (round-robin); 2 XCDs per batch ----
    int w = blockIdx.x;                 // [0,256)
    int xcd = w & 7, slot = w >> 3;     // slot in [0,32)
    int b = xcd >> 1;
    int i0 = (slot * 2 + (xcd & 1)) * 64;

    int wv = threadIdx.x >> 6, lane = threadIdx.x & 63;
    int lr = lane & 15, lc = lane >> 4;

    __shared__ u16 P_lds[2][64 * 128];  // 2 x 16KB, swizzled: byte = i*256 + (jb ^ ((i&7)<<4))
    __shared__ float s_l[64][8];        // per-wave partial row sums

    const u16* qTb = qT + (size_t)b * N_ * D_;
    const u16* kTb = kT + (size_t)b * N_ * D_;
    const u16* vb  = v  + (size_t)b * C_ * N_;

    // Q fragments: 64 i x 64 d, held all kernel. B-operand layout: row=lr, k-chunk=lc*8.
    short8 qf[4][2];
#pragma unroll
    for (int mt = 0; mt < 4; mt++)
#pragma unroll
        for (int kd = 0; kd < 2; kd++)
            qf[mt][kd] = *reinterpret_cast<const short8*>(
                &qTb[(size_t)(i0 + mt * 16 + lr) * D_ + kd * 32 + lc * 8]);

    f32x4 acc[4][4] = {};               // [mt][ct]: O slice 64 i x 64 c (unnormalized)
    float lsum[4] = {0.f, 0.f, 0.f, 0.f};

    // prefetch K for jt=0: wave's 16-j slice
    short8 kf0, kf1, kf0n, kf1n;
    {
        const u16* kp = kTb + (size_t)(wv * 16 + lr) * D_;
        kf0 = *reinterpret_cast<const short8*>(kp + lc * 8);
        kf1 = *reinterpret_cast<const short8*>(kp + 32 + lc * 8);
    }

    for (int jt = 0; jt < 32; jt++) {
        char* pb = reinterpret_cast<char*>(P_lds[jt & 1]);
        // ---- S phase: swapped mfma(K,Q): lane holds S[i = mt*16+lr][j = wv*16+lc*4+r] ----
#pragma unroll
        for (int mt = 0; mt < 4; mt++) {
            f32x4 s = {};
            s = MFMA16(kf0, qf[mt][0], s);
            s = MFMA16(kf1, qf[mt][1], s);
            s16x4 pk;
            float ps = 0.f;
#pragma unroll
            for (int r = 0; r < 4; r++) {
                float p = __expf(s[r]);
                ps += p;
                pk[r] = (short)f2bf(p);
            }
            lsum[mt] += ps;
            int i = mt * 16 + lr;
            int byte_off = i * 256 + ((wv * 32 + lc * 8) ^ ((i & 7) << 4));
            *reinterpret_cast<s16x4*>(pb + byte_off) = pk;
        }
        // ---- prefetch K for jt+1 (hide L2 latency under PV) ----
        if (jt < 31) {
            const u16* kp = kTb + (size_t)((jt + 1) * 128 + wv * 16 + lr) * D_;
            kf0n = *reinterpret_cast<const short8*>(kp + lc * 8);
            kf1n = *reinterpret_cast<const short8*>(kp + 32 + lc * 8);
        }
        __syncthreads();   // single barrier per jt (double-buffered P)
        // ---- PV phase: O[64 i][c-slice 64] += P[64][128] * V[c][128 j] ----
#pragma unroll
        for (int kt = 0; kt < 4; kt++) {
            short8 pf[4];
#pragma unroll
            for (int mt = 0; mt < 4; mt++) {
                int i = mt * 16 + lr;
                int byte_off = i * 256 + (((kt * 64) + lc * 16) ^ ((i & 7) << 4));
                pf[mt] = *reinterpret_cast<const short8*>(pb + byte_off);
            }
#pragma unroll
            for (int ct = 0; ct < 4; ct++) {
                int c = wv * 64 + ct * 16 + lr;
                short8 vf = *reinterpret_cast<const short8*>(
                    &vb[(size_t)c * N_ + jt * 128 + kt * 32 + lc * 8]);
#pragma unroll
                for (int mt = 0; mt < 4; mt++)
                    acc[mt][ct] = MFMA16(pf[mt], vf, acc[mt][ct]);
            }
        }
        kf0 = kf0n; kf1 = kf1n;
    }

    // ---- row-sum reduce: lane has lsum[mt] for i = mt*16+lr over its (wv, lc) j-set ----
#pragma unroll
    for (int mt = 0; mt < 4; mt++) {
        float l_ = lsum[mt];
        l_ += __shfl_xor(l_, 16);
        l_ += __shfl_xor(l_, 32);
        if (lc == 0) s_l[mt * 16 + lr][wv] = l_;
    }
    __syncthreads();

    // ---- epilogue: out = gamma * (O / l) + x ----
    float g = gamma_p[0];
    const float* xb = x + (size_t)b * C_ * N_;
    float* ob = out + (size_t)b * C_ * N_;
#pragma unroll
    for (int mt = 0; mt < 4; mt++) {
        float linv[4];
#pragma unroll
        for (int r = 0; r < 4; r++) {
            int i = mt * 16 + lc * 4 + r;
            float4 l0 = *reinterpret_cast<const float4*>(&s_l[i][0]);
            float4 l1 = *reinterpret_cast<const float4*>(&s_l[i][4]);
            linv[r] = 1.0f / (l0.x + l0.y + l0.z + l0.w + l1.x + l1.y + l1.z + l1.w);
        }
#pragma unroll
        for (int ct = 0; ct < 4; ct++) {
            int c = wv * 64 + ct * 16 + lr;
            size_t off = (size_t)c * N_ + i0 + mt * 16 + lc * 4;
            float4 xv = *reinterpret_cast<const float4*>(&xb[off]);
            float4 ov;
            ov.x = g * acc[mt][ct][0] * linv[0] + xv.x;
            ov.y = g * acc[mt][ct][1] * linv[1] + xv.y;
            ov.z = g * acc[mt][ct][2] * linv[2] + xv.z;
            ov.w = g * acc[mt][ct][3] * linv[3] + xv.w;
            *reinterpret_cast<float4*>(&ob[off]) = ov;
        }
    }
}

extern "C" void kernel_launch(void* const* d_in, const int* in_sizes, int n_in,
                              void* d_out, int out_size, void* d_ws, size_t ws_size,
                              hipStream_t stream) {
    const float* x     = (const float*)d_in[0];
    const float* Wq    = (const float*)d_in[1];
    const float* bq    = (const float*)d_in[2];
    const float* Wk    = (const float*)d_in[3];
    const float* bk    = (const float*)d_in[4];
    const float* Wv    = (const float*)d_in[5];
    const float* bv    = (const float*)d_in[6];
    const float* gamma = (const float*)d_in[7];
    float* out = (float*)d_out;

    char* ws = (char*)d_ws;
    // layout (bytes): xT 16MB | Wcat 640KB | biascat 2.5KB | qT 2MB | kT 2MB | v 16MB
    u16*   xT      = (u16*)ws;
    u16*   Wcat    = (u16*)(ws + (size_t)16777216);
    float* biascat = (float*)(ws + (size_t)16777216 + 655360);
    u16*   qT      = (u16*)(ws + (size_t)16777216 + 655360 + 4096);
    u16*   kT      = qT + (size_t)B_ * N_ * D_;
    u16*   v       = kT + (size_t)B_ * N_ * D_;

    prep_w<<<1280, 256, 0, stream>>>(Wq, bq, Wk, bk, Wv, bv, Wcat, biascat);
    transpose_x<<<dim3(N_ / 32, C_ / 32, B_), 256, 0, stream>>>(x, xT);
    proj_gemm<<<dim3(N_ / 256, 640 / 64, B_), 256, 0, stream>>>(Wcat, biascat, xT, qT, kT, v);
    attn<<<256, 512, 0, stream>>>(qT, kT, v, x, gamma, out);
}

// Round 3
// 234.298 us; speedup vs baseline: 1.6406x; 1.0044x over previous
//
#include <hip/hip_runtime.h>
#include <stdint.h>

typedef unsigned short u16;
typedef __attribute__((ext_vector_type(8))) short short8;   // 8 bf16 = 4 VGPR
typedef __attribute__((ext_vector_type(4))) short s16x4;    // 4 bf16 = 2 VGPR
typedef __attribute__((ext_vector_type(4))) float f32x4;

#define MFMA16(a,b,c) __builtin_amdgcn_mfma_f32_16x16x32_bf16(a,b,c,0,0,0)

constexpr int B_ = 4, C_ = 512, N_ = 4096, D_ = 64;  // D_ = CQK = C/8

static __device__ __forceinline__ u16 f2bf(float f) {
    uint32_t u = __builtin_bit_cast(uint32_t, f);
    uint32_t r = (u + 0x7FFFu + ((u >> 16) & 1u)) >> 16;   // RNE
    return (u16)r;
}

// ---------------- prep: Wcat bf16 [640][512] (q rows 0-63, k 64-127, v 128-639) + biascat ----
__global__ void prep_w(const float* Wq, const float* bq, const float* Wk, const float* bk,
                       const float* Wv, const float* bv, u16* Wcat, float* biascat) {
    int idx = blockIdx.x * 256 + threadIdx.x;
    if (idx < 640 * 512) {
        int row = idx >> 9, col = idx & 511;
        float w;
        if (row < 64)        w = Wq[row * 512 + col];
        else if (row < 128)  w = Wk[(row - 64) * 512 + col];
        else                 w = Wv[(row - 128) * 512 + col];
        Wcat[idx] = f2bf(w);
    }
    if (idx < 640) {
        float bb;
        if (idx < 64)        bb = bq[idx];
        else if (idx < 128)  bb = bk[idx - 64];
        else                 bb = bv[idx - 128];
        biascat[idx] = bb;
    }
}

// ---------------- transpose x [B][C][N] f32 -> xT [B][N][C] bf16 ----------------
__global__ void transpose_x(const float* __restrict__ x, u16* __restrict__ xT) {
    __shared__ float tile[32][33];
    int n0 = blockIdx.x * 32, c0 = blockIdx.y * 32, b = blockIdx.z;
    int tx = threadIdx.x & 31, ty = threadIdx.x >> 5;       // ty 0..7
    const float* xb = x + (size_t)b * C_ * N_;
#pragma unroll
    for (int r = 0; r < 4; r++) {
        int c = ty * 4 + r;
        tile[c][tx] = xb[(size_t)(c0 + c) * N_ + n0 + tx];
    }
    __syncthreads();
    u16* xTb = xT + (size_t)b * N_ * C_;
#pragma unroll
    for (int r = 0; r < 4; r++) {
        int n = ty * 4 + r;
        xTb[(size_t)(n0 + n) * C_ + c0 + tx] = f2bf(tile[tx][n]);
    }
}

// ---------------- projection GEMM: Y[640][4096] = Wcat x X_b^T, per batch --------
// register double-buffered K-loop; writes qT/kT [B][N][64] and v [B][C][N]
__global__ __launch_bounds__(256) void proj_gemm(const u16* __restrict__ Wcat,
                                                 const float* __restrict__ biascat,
                                                 const u16* __restrict__ xT,
                                                 u16* __restrict__ qT, u16* __restrict__ kT,
                                                 u16* __restrict__ v) {
    int b = blockIdx.z;
    int m0 = blockIdx.y * 64;
    int wave = threadIdx.x >> 6, lane = threadIdx.x & 63;
    int n0 = blockIdx.x * 256 + wave * 64;
    int lr = lane & 15, lc = lane >> 4;
    const u16* xTb = xT + (size_t)b * N_ * C_;

    f32x4 acc[4][4] = {};   // [ma][na]
    short8 aF[4], bF[4], aFn[4], bFn[4];
#pragma unroll
    for (int ma = 0; ma < 4; ma++)
        aF[ma] = *reinterpret_cast<const short8*>(&Wcat[(size_t)(m0 + ma * 16 + lr) * 512 + lc * 8]);
#pragma unroll
    for (int na = 0; na < 4; na++)
        bF[na] = *reinterpret_cast<const short8*>(&xTb[(size_t)(n0 + na * 16 + lr) * 512 + lc * 8]);

    for (int k0 = 0; k0 < 512; k0 += 32) {
        if (k0 < 480) {
            int kn = k0 + 32;
#pragma unroll
            for (int ma = 0; ma < 4; ma++)
                aFn[ma] = *reinterpret_cast<const short8*>(&Wcat[(size_t)(m0 + ma * 16 + lr) * 512 + kn + lc * 8]);
#pragma unroll
            for (int na = 0; na < 4; na++)
                bFn[na] = *reinterpret_cast<const short8*>(&xTb[(size_t)(n0 + na * 16 + lr) * 512 + kn + lc * 8]);
        }
#pragma unroll
        for (int ma = 0; ma < 4; ma++)
#pragma unroll
            for (int na = 0; na < 4; na++)
                acc[ma][na] = MFMA16(aF[ma], bF[na], acc[ma][na]);
#pragma unroll
        for (int t = 0; t < 4; t++) { aF[t] = aFn[t]; bF[t] = bFn[t]; }
    }
#pragma unroll
    for (int ma = 0; ma < 4; ma++) {
#pragma unroll
        for (int r = 0; r < 4; r++) {
            int m = m0 + ma * 16 + lc * 4 + r;
            float bias = biascat[m];
#pragma unroll
            for (int na = 0; na < 4; na++) {
                int n = n0 + na * 16 + lr;
                u16 hv = f2bf(acc[ma][na][r] + bias);
                if (m < 64)
                    qT[((size_t)b * N_ + n) * D_ + m] = hv;
                else if (m < 128)
                    kT[((size_t)b * N_ + n) * D_ + (m - 64)] = hv;
                else
                    v[((size_t)b * C_ + (m - 128)) * (size_t)N_ + n] = hv;
            }
        }
    }
}

// ---------------- fused attention, one pass, no max-subtraction, c-split x2 ----------------
// Block: 64 i-rows x 256-c half; 4 waves; wave owns c-slice [c0+wv*64, +64) and ALL 64 i.
// Per 128-j tile: wave computes S^T for its 32-j slice via SWAPPED mfma(K,Q); P=exp(S)
// (unnormalized) -> double-buffered XOR-swizzled LDS tile; PV accumulates from register-
// prefetched V. QK^T is duplicated across the 2 c-half blocks (cheap) so each block has
// the full row-sums l. Grid 512 = 2 blocks/CU -> independent barriers hide latency.
// XCD map: xcd pair <-> batch so V-half (2MB) + K (512KB) stay in one XCD's L2.
__global__ __launch_bounds__(256) void attn(const u16* __restrict__ qT, const u16* __restrict__ kT,
                                            const u16* __restrict__ v, const float* __restrict__ x,
                                            const float* __restrict__ gamma_p, float* __restrict__ out) {
    int w = blockIdx.x;                 // [0,512)
    int xcd = w & 7, slot = w >> 3;     // slot in [0,64)
    int b = xcd >> 1;
    int chalf = xcd & 1;
    int i0 = slot * 64;
    int c0 = chalf * 256;

    int wv = threadIdx.x >> 6, lane = threadIdx.x & 63;
    int lr = lane & 15, lc = lane >> 4;

    __shared__ u16 P_lds[2][64 * 128];  // 2 x 16KB, swizzled: byte = i*256 + (jb ^ ((i&7)<<4))
    __shared__ float s_l[64][4];        // per-wave partial row sums

    const u16* qTb = qT + (size_t)b * N_ * D_;
    const u16* kTb = kT + (size_t)b * N_ * D_;
    const u16* vb  = v  + (size_t)b * C_ * N_;

    // Q fragments: 64 i x 64 d, held all kernel (B-operand: row=lr, k-chunk=lc*8)
    short8 qf[4][2];
#pragma unroll
    for (int mt = 0; mt < 4; mt++)
#pragma unroll
        for (int kd = 0; kd < 2; kd++)
            qf[mt][kd] = *reinterpret_cast<const short8*>(
                &qTb[(size_t)(i0 + mt * 16 + lr) * D_ + kd * 32 + lc * 8]);

    f32x4 acc[4][4] = {};               // [mt][ct]: O slice 64 i x 64 c (unnormalized)
    float lsum[4] = {0.f, 0.f, 0.f, 0.f};

    // prefetch K for jt=0: wave's 32-j slice (2 x 16-j fragments)
    short8 kf[2][2], kfn[2][2];
#pragma unroll
    for (int jb = 0; jb < 2; jb++)
#pragma unroll
        for (int kd = 0; kd < 2; kd++)
            kf[jb][kd] = *reinterpret_cast<const short8*>(
                &kTb[(size_t)(wv * 32 + jb * 16 + lr) * D_ + kd * 32 + lc * 8]);

    for (int jt = 0; jt < 32; jt++) {
        char* pb = reinterpret_cast<char*>(P_lds[jt & 1]);

        // ---- V prefetch for THIS jt: issued before S phase, consumed after barrier ----
        short8 vf[16];
#pragma unroll
        for (int kt = 0; kt < 4; kt++)
#pragma unroll
            for (int ct = 0; ct < 4; ct++)
                vf[kt * 4 + ct] = *reinterpret_cast<const short8*>(
                    &vb[(size_t)(c0 + wv * 64 + ct * 16 + lr) * N_ + jt * 128 + kt * 32 + lc * 8]);

        // ---- S phase: swapped mfma(K,Q): lane holds S[i=mt*16+lr][j=wv*32+jb*16+lc*4+r] ----
#pragma unroll
        for (int jb = 0; jb < 2; jb++)
#pragma unroll
        for (int mt = 0; mt < 4; mt++) {
            f32x4 s = {};
            s = MFMA16(kf[jb][0], qf[mt][0], s);
            s = MFMA16(kf[jb][1], qf[mt][1], s);
            s16x4 pk;
            float ps = 0.f;
#pragma unroll
            for (int r = 0; r < 4; r++) {
                float p = __expf(s[r]);
                ps += p;
                pk[r] = (short)f2bf(p);
            }
            lsum[mt] += ps;
            int i = mt * 16 + lr;
            int byte_off = i * 256 + ((wv * 64 + jb * 32 + lc * 8) ^ ((i & 7) << 4));
            *reinterpret_cast<s16x4*>(pb + byte_off) = pk;
        }
        // ---- prefetch K for jt+1 ----
        if (jt < 31) {
#pragma unroll
            for (int jb = 0; jb < 2; jb++)
#pragma unroll
                for (int kd = 0; kd < 2; kd++)
                    kfn[jb][kd] = *reinterpret_cast<const short8*>(
                        &kTb[(size_t)((jt + 1) * 128 + wv * 32 + jb * 16 + lr) * D_ + kd * 32 + lc * 8]);
        }
        __syncthreads();   // single barrier per jt (double-buffered P)

        // ---- PV phase: O[64 i][64 c] += P[64][128] * V[c][128 j] ----
#pragma unroll
        for (int kt = 0; kt < 4; kt++) {
            short8 pf[4];
#pragma unroll
            for (int mt = 0; mt < 4; mt++) {
                int i = mt * 16 + lr;
                int byte_off = i * 256 + (((kt * 64) + lc * 16) ^ ((i & 7) << 4));
                pf[mt] = *reinterpret_cast<const short8*>(pb + byte_off);
            }
#pragma unroll
            for (int ct = 0; ct < 4; ct++)
#pragma unroll
                for (int mt = 0; mt < 4; mt++)
                    acc[mt][ct] = MFMA16(pf[mt], vf[kt * 4 + ct], acc[mt][ct]);
        }
#pragma unroll
        for (int jb = 0; jb < 2; jb++)
#pragma unroll
            for (int kd = 0; kd < 2; kd++)
                kf[jb][kd] = kfn[jb][kd];
    }

    // ---- row-sum reduce: lane has lsum[mt] for i = mt*16+lr over its (wv,jb,lc) j-set ----
#pragma unroll
    for (int mt = 0; mt < 4; mt++) {
        float l_ = lsum[mt];
        l_ += __shfl_xor(l_, 16);
        l_ += __shfl_xor(l_, 32);
        if (lc == 0) s_l[mt * 16 + lr][wv] = l_;
    }
    __syncthreads();

    // ---- epilogue: out = gamma * (O / l) + x ----
    float g = gamma_p[0];
    const float* xb = x + (size_t)b * C_ * N_;
    float* ob = out + (size_t)b * C_ * N_;
#pragma unroll
    for (int mt = 0; mt < 4; mt++) {
        float linv[4];
#pragma unroll
        for (int r = 0; r < 4; r++) {
            int i = mt * 16 + lc * 4 + r;
            float4 lv = *reinterpret_cast<const float4*>(&s_l[i][0]);
            linv[r] = 1.0f / (lv.x + lv.y + lv.z + lv.w);
        }
#pragma unroll
        for (int ct = 0; ct < 4; ct++) {
            int c = c0 + wv * 64 + ct * 16 + lr;
            size_t off = (size_t)c * N_ + i0 + mt * 16 + lc * 4;
            float4 xv = *reinterpret_cast<const float4*>(&xb[off]);
            float4 ov;
            ov.x = g * acc[mt][ct][0] * linv[0] + xv.x;
            ov.y = g * acc[mt][ct][1] * linv[1] + xv.y;
            ov.z = g * acc[mt][ct][2] * linv[2] + xv.z;
            ov.w = g * acc[mt][ct][3] * linv[3] + xv.w;
            *reinterpret_cast<float4*>(&ob[off]) = ov;
        }
    }
}

extern "C" void kernel_launch(void* const* d_in, const int* in_sizes, int n_in,
                              void* d_out, int out_size, void* d_ws, size_t ws_size,
                              hipStream_t stream) {
    const float* x     = (const float*)d_in[0];
    const float* Wq    = (const float*)d_in[1];
    const float* bq    = (const float*)d_in[2];
    const float* Wk    = (const float*)d_in[3];
    const float* bk    = (const float*)d_in[4];
    const float* Wv    = (const float*)d_in[5];
    const float* bv    = (const float*)d_in[6];
    const float* gamma = (const float*)d_in[7];
    float* out = (float*)d_out;

    char* ws = (char*)d_ws;
    // layout (bytes): xT 16MB | Wcat 640KB | biascat 2.5KB | qT 2MB | kT 2MB | v 16MB
    u16*   xT      = (u16*)ws;
    u16*   Wcat    = (u16*)(ws + (size_t)16777216);
    float* biascat = (float*)(ws + (size_t)16777216 + 655360);
    u16*   qT      = (u16*)(ws + (size_t)16777216 + 655360 + 4096);
    u16*   kT      = qT + (size_t)B_ * N_ * D_;
    u16*   v       = kT + (size_t)B_ * N_ * D_;

    prep_w<<<1280, 256, 0, stream>>>(Wq, bq, Wk, bk, Wv, bv, Wcat, biascat);
    transpose_x<<<dim3(N_ / 32, C_ / 32, B_), 256, 0, stream>>>(x, xT);
    proj_gemm<<<dim3(N_ / 256, 640 / 64, B_), 256, 0, stream>>>(Wcat, biascat, xT, qT, kT, v);
    attn<<<512, 256, 0, stream>>>(qT, kT, v, x, gamma, out);
}

// Round 4
// 223.033 us; speedup vs baseline: 1.7235x; 1.0505x over previous
//
#include <hip/hip_runtime.h>
#include <stdint.h>

typedef unsigned short u16;
typedef __attribute__((ext_vector_type(8))) short short8;   // 8 bf16 = 4 VGPR
typedef __attribute__((ext_vector_type(4))) short s16x4;    // 4 bf16 = 2 VGPR
typedef __attribute__((ext_vector_type(4))) float f32x4;

#define MFMA16(a,b,c) __builtin_amdgcn_mfma_f32_16x16x32_bf16(a,b,c,0,0,0)

constexpr int B_ = 4, C_ = 512, N_ = 4096, D_ = 64;  // D_ = CQK = C/8

static __device__ __forceinline__ u16 f2bf(float f) {
    uint32_t u = __builtin_bit_cast(uint32_t, f);
    uint32_t r = (u + 0x7FFFu + ((u >> 16) & 1u)) >> 16;   // RNE
    return (u16)r;
}

// ---------------- prep: Wcat bf16 [640][512] + biascat; Wq/bq pre-scaled by log2(e) ----
// so attention S' = log2(e) * (q.k) and p = exp2(S') = exp(q.k) with a single v_exp_f32.
__global__ void prep_w(const float* Wq, const float* bq, const float* Wk, const float* bk,
                       const float* Wv, const float* bv, u16* Wcat, float* biascat) {
    const float LOG2E = 1.44269504088896340736f;
    int idx = blockIdx.x * 256 + threadIdx.x;
    if (idx < 640 * 512) {
        int row = idx >> 9, col = idx & 511;
        float w;
        if (row < 64)        w = Wq[row * 512 + col] * LOG2E;
        else if (row < 128)  w = Wk[(row - 64) * 512 + col];
        else                 w = Wv[(row - 128) * 512 + col];
        Wcat[idx] = f2bf(w);
    }
    if (idx < 640) {
        float bb;
        if (idx < 64)        bb = bq[idx] * LOG2E;
        else if (idx < 128)  bb = bk[idx - 64];
        else                 bb = bv[idx - 128];
        biascat[idx] = bb;
    }
}

// ---------------- transpose x [B][C][N] f32 -> xT [B][N][C] bf16 ----------------
__global__ void transpose_x(const float* __restrict__ x, u16* __restrict__ xT) {
    __shared__ float tile[32][33];
    int n0 = blockIdx.x * 32, c0 = blockIdx.y * 32, b = blockIdx.z;
    int tx = threadIdx.x & 31, ty = threadIdx.x >> 5;       // ty 0..7
    const float* xb = x + (size_t)b * C_ * N_;
#pragma unroll
    for (int r = 0; r < 4; r++) {
        int c = ty * 4 + r;
        tile[c][tx] = xb[(size_t)(c0 + c) * N_ + n0 + tx];
    }
    __syncthreads();
    u16* xTb = xT + (size_t)b * N_ * C_;
#pragma unroll
    for (int r = 0; r < 4; r++) {
        int n = ty * 4 + r;
        xTb[(size_t)(n0 + n) * C_ + c0 + tx] = f2bf(tile[tx][n]);
    }
}

// ---------------- projection GEMM: Y[640][4096] = Wcat x X_b^T, per batch --------
// register double-buffered K-loop; writes qT/kT [B][N][64] and v [B][C][N]
__global__ __launch_bounds__(256) void proj_gemm(const u16* __restrict__ Wcat,
                                                 const float* __restrict__ biascat,
                                                 const u16* __restrict__ xT,
                                                 u16* __restrict__ qT, u16* __restrict__ kT,
                                                 u16* __restrict__ v) {
    int b = blockIdx.z;
    int m0 = blockIdx.y * 64;
    int wave = threadIdx.x >> 6, lane = threadIdx.x & 63;
    int n0 = blockIdx.x * 256 + wave * 64;
    int lr = lane & 15, lc = lane >> 4;
    const u16* xTb = xT + (size_t)b * N_ * C_;

    f32x4 acc[4][4] = {};   // [ma][na]
    short8 aF[4], bF[4], aFn[4], bFn[4];
#pragma unroll
    for (int ma = 0; ma < 4; ma++)
        aF[ma] = *reinterpret_cast<const short8*>(&Wcat[(size_t)(m0 + ma * 16 + lr) * 512 + lc * 8]);
#pragma unroll
    for (int na = 0; na < 4; na++)
        bF[na] = *reinterpret_cast<const short8*>(&xTb[(size_t)(n0 + na * 16 + lr) * 512 + lc * 8]);

    for (int k0 = 0; k0 < 512; k0 += 32) {
        if (k0 < 480) {
            int kn = k0 + 32;
#pragma unroll
            for (int ma = 0; ma < 4; ma++)
                aFn[ma] = *reinterpret_cast<const short8*>(&Wcat[(size_t)(m0 + ma * 16 + lr) * 512 + kn + lc * 8]);
#pragma unroll
            for (int na = 0; na < 4; na++)
                bFn[na] = *reinterpret_cast<const short8*>(&xTb[(size_t)(n0 + na * 16 + lr) * 512 + kn + lc * 8]);
        }
#pragma unroll
        for (int ma = 0; ma < 4; ma++)
#pragma unroll
            for (int na = 0; na < 4; na++)
                acc[ma][na] = MFMA16(aF[ma], bF[na], acc[ma][na]);
#pragma unroll
        for (int t = 0; t < 4; t++) { aF[t] = aFn[t]; bF[t] = bFn[t]; }
    }
#pragma unroll
    for (int ma = 0; ma < 4; ma++) {
#pragma unroll
        for (int r = 0; r < 4; r++) {
            int m = m0 + ma * 16 + lc * 4 + r;
            float bias = biascat[m];
#pragma unroll
            for (int na = 0; na < 4; na++) {
                int n = n0 + na * 16 + lr;
                u16 hv = f2bf(acc[ma][na][r] + bias);
                if (m < 64)
                    qT[((size_t)b * N_ + n) * D_ + m] = hv;
                else if (m < 128)
                    kT[((size_t)b * N_ + n) * D_ + (m - 64)] = hv;
                else
                    v[((size_t)b * C_ + (m - 128)) * (size_t)N_ + n] = hv;
            }
        }
    }
}

// ---------------- fused attention, one pass, no max-subtraction ----------------
// Block: 64 i-rows (BM=64); 8 waves; wave w owns c-slice [w*64,+64) and ALL 64 i.
// Pipeline per 128-j tile: (A) issue this tile's 16 V dwordx4 loads, (B) issue K
// loads for jt+1, (C) S phase = swapped mfma(K,Q) + exp2 + pack -> swizzled LDS,
// (D) barrier, (E) PV MFMA cluster (setprio-wrapped) consuming prefetched V.
// V/K L2 latency hides under (C)+(D). XCD map: 2 XCDs per batch (V[b] L2-resident).
__global__ __launch_bounds__(512) void attn(const u16* __restrict__ qT, const u16* __restrict__ kT,
                                            const u16* __restrict__ v, const float* __restrict__ x,
                                            const float* __restrict__ gamma_p, float* __restrict__ out) {
    int w = blockIdx.x;                 // [0,256)
    int xcd = w & 7, slot = w >> 3;     // slot in [0,32)
    int b = xcd >> 1;
    int i0 = (slot * 2 + (xcd & 1)) * 64;

    int wv = threadIdx.x >> 6, lane = threadIdx.x & 63;
    int lr = lane & 15, lc = lane >> 4;

    __shared__ u16 P_lds[2][64 * 128];  // 2 x 16KB, swizzled: byte = i*256 + (jb ^ ((i&7)<<4))
    __shared__ float s_l[64][8];        // per-wave partial row sums

    const u16* qTb = qT + (size_t)b * N_ * D_;
    const u16* kTb = kT + (size_t)b * N_ * D_;
    const u16* vb  = v  + (size_t)b * C_ * N_;

    // Q fragments: 64 i x 64 d, held all kernel (B-operand: row=lr, k-chunk=lc*8)
    short8 qf[4][2];
#pragma unroll
    for (int mt = 0; mt < 4; mt++)
#pragma unroll
        for (int kd = 0; kd < 2; kd++)
            qf[mt][kd] = *reinterpret_cast<const short8*>(
                &qTb[(size_t)(i0 + mt * 16 + lr) * D_ + kd * 32 + lc * 8]);

    f32x4 acc[4][4] = {};               // [mt][ct]: O slice 64 i x 64 c (unnormalized)
    float lsum[4] = {0.f, 0.f, 0.f, 0.f};

    // prefetch K for jt=0: wave's 16-j slice
    short8 kf0, kf1, kf0n, kf1n;
    {
        const u16* kp = kTb + (size_t)(wv * 16 + lr) * D_;
        kf0 = *reinterpret_cast<const short8*>(kp + lc * 8);
        kf1 = *reinterpret_cast<const short8*>(kp + 32 + lc * 8);
    }

    for (int jt = 0; jt < 32; jt++) {
        char* pb = reinterpret_cast<char*>(P_lds[jt & 1]);

        // ---- (A) V prefetch for THIS jt: issued first, consumed after the barrier ----
        short8 vf[16];
#pragma unroll
        for (int kt = 0; kt < 4; kt++)
#pragma unroll
            for (int ct = 0; ct < 4; ct++)
                vf[kt * 4 + ct] = *reinterpret_cast<const short8*>(
                    &vb[(size_t)(wv * 64 + ct * 16 + lr) * N_ + jt * 128 + kt * 32 + lc * 8]);

        // ---- (B) K prefetch for jt+1 ----
        if (jt < 31) {
            const u16* kp = kTb + (size_t)((jt + 1) * 128 + wv * 16 + lr) * D_;
            kf0n = *reinterpret_cast<const short8*>(kp + lc * 8);
            kf1n = *reinterpret_cast<const short8*>(kp + 32 + lc * 8);
        }

        // ---- (C) S phase: swapped mfma(K,Q): lane holds S'[i=mt*16+lr][j=wv*16+lc*4+r] ----
#pragma unroll
        for (int mt = 0; mt < 4; mt++) {
            f32x4 s = {};
            s = MFMA16(kf0, qf[mt][0], s);
            s = MFMA16(kf1, qf[mt][1], s);
            s16x4 pk;
            float ps = 0.f;
#pragma unroll
            for (int r = 0; r < 4; r++) {
                float p = __builtin_amdgcn_exp2f(s[r]);   // exp(q.k): log2e folded into Wq
                ps += p;
                pk[r] = (short)f2bf(p);
            }
            lsum[mt] += ps;
            int i = mt * 16 + lr;
            int byte_off = i * 256 + ((wv * 32 + lc * 8) ^ ((i & 7) << 4));
            *reinterpret_cast<s16x4*>(pb + byte_off) = pk;
        }
        __syncthreads();   // (D) single barrier per jt (double-buffered P)

        // ---- (E) PV phase: O[64 i][64 c] += P[64][128] * V[c][128 j] ----
        __builtin_amdgcn_s_setprio(1);
#pragma unroll
        for (int kt = 0; kt < 4; kt++) {
            short8 pf[4];
#pragma unroll
            for (int mt = 0; mt < 4; mt++) {
                int i = mt * 16 + lr;
                int byte_off = i * 256 + (((kt * 64) + lc * 16) ^ ((i & 7) << 4));
                pf[mt] = *reinterpret_cast<const short8*>(pb + byte_off);
            }
#pragma unroll
            for (int ct = 0; ct < 4; ct++)
#pragma unroll
                for (int mt = 0; mt < 4; mt++)
                    acc[mt][ct] = MFMA16(pf[mt], vf[kt * 4 + ct], acc[mt][ct]);
        }
        __builtin_amdgcn_s_setprio(0);
        kf0 = kf0n; kf1 = kf1n;
    }

    // ---- row-sum reduce: lane has lsum[mt] for i = mt*16+lr over its (wv, lc) j-set ----
#pragma unroll
    for (int mt = 0; mt < 4; mt++) {
        float l_ = lsum[mt];
        l_ += __shfl_xor(l_, 16);
        l_ += __shfl_xor(l_, 32);
        if (lc == 0) s_l[mt * 16 + lr][wv] = l_;
    }
    __syncthreads();

    // ---- epilogue: out = gamma * (O / l) + x ----
    float g = gamma_p[0];
    const float* xb = x + (size_t)b * C_ * N_;
    float* ob = out + (size_t)b * C_ * N_;
#pragma unroll
    for (int mt = 0; mt < 4; mt++) {
        float linv[4];
#pragma unroll
        for (int r = 0; r < 4; r++) {
            int i = mt * 16 + lc * 4 + r;
            float4 l0 = *reinterpret_cast<const float4*>(&s_l[i][0]);
            float4 l1 = *reinterpret_cast<const float4*>(&s_l[i][4]);
            linv[r] = 1.0f / (l0.x + l0.y + l0.z + l0.w + l1.x + l1.y + l1.z + l1.w);
        }
#pragma unroll
        for (int ct = 0; ct < 4; ct++) {
            int c = wv * 64 + ct * 16 + lr;
            size_t off = (size_t)c * N_ + i0 + mt * 16 + lc * 4;
            float4 xv = *reinterpret_cast<const float4*>(&xb[off]);
            float4 ov;
            ov.x = g * acc[mt][ct][0] * linv[0] + xv.x;
            ov.y = g * acc[mt][ct][1] * linv[1] + xv.y;
            ov.z = g * acc[mt][ct][2] * linv[2] + xv.z;
            ov.w = g * acc[mt][ct][3] * linv[3] + xv.w;
            *reinterpret_cast<float4*>(&ob[off]) = ov;
        }
    }
}

extern "C" void kernel_launch(void* const* d_in, const int* in_sizes, int n_in,
                              void* d_out, int out_size, void* d_ws, size_t ws_size,
                              hipStream_t stream) {
    const float* x     = (const float*)d_in[0];
    const float* Wq    = (const float*)d_in[1];
    const float* bq    = (const float*)d_in[2];
    const float* Wk    = (const float*)d_in[3];
    const float* bk    = (const float*)d_in[4];
    const float* Wv    = (const float*)d_in[5];
    const float* bv    = (const float*)d_in[6];
    const float* gamma = (const float*)d_in[7];
    float* out = (float*)d_out;

    char* ws = (char*)d_ws;
    // layout (bytes): xT 16MB | Wcat 640KB | biascat 2.5KB | qT 2MB | kT 2MB | v 16MB
    u16*   xT      = (u16*)ws;
    u16*   Wcat    = (u16*)(ws + (size_t)16777216);
    float* biascat = (float*)(ws + (size_t)16777216 + 655360);
    u16*   qT      = (u16*)(ws + (size_t)16777216 + 655360 + 4096);
    u16*   kT      = qT + (size_t)B_ * N_ * D_;
    u16*   v       = kT + (size_t)B_ * N_ * D_;

    prep_w<<<1280, 256, 0, stream>>>(Wq, bq, Wk, bk, Wv, bv, Wcat, biascat);
    transpose_x<<<dim3(N_ / 32, C_ / 32, B_), 256, 0, stream>>>(x, xT);
    proj_gemm<<<dim3(N_ / 256, 640 / 64, B_), 256, 0, stream>>>(Wcat, biascat, xT, qT, kT, v);
    attn<<<256, 512, 0, stream>>>(qT, kT, v, x, gamma, out);
}

// Round 5
// 219.883 us; speedup vs baseline: 1.7482x; 1.0143x over previous
//
#include <hip/hip_runtime.h>
#include <stdint.h>

typedef unsigned short u16;
typedef __attribute__((ext_vector_type(8))) short short8;   // 8 bf16 = 4 VGPR
typedef __attribute__((ext_vector_type(4))) short s16x4;    // 4 bf16 = 2 VGPR
typedef __attribute__((ext_vector_type(4))) float f32x4;

#define MFMA16(a,b,c) __builtin_amdgcn_mfma_f32_16x16x32_bf16(a,b,c,0,0,0)

constexpr int B_ = 4, C_ = 512, N_ = 4096, D_ = 64;  // D_ = CQK = C/8

static __device__ __forceinline__ u16 f2bf(float f) {
    uint32_t u = __builtin_bit_cast(uint32_t, f);
    uint32_t r = (u + 0x7FFFu + ((u >> 16) & 1u)) >> 16;   // RNE
    return (u16)r;
}

// ---------------- prep: Wcat bf16 [640][512] + biascat; Wq/bq pre-scaled by log2(e) ----
__global__ void prep_w(const float* Wq, const float* bq, const float* Wk, const float* bk,
                       const float* Wv, const float* bv, u16* Wcat, float* biascat) {
    const float LOG2E = 1.44269504088896340736f;
    int idx = blockIdx.x * 256 + threadIdx.x;
    if (idx < 640 * 512) {
        int row = idx >> 9, col = idx & 511;
        float w;
        if (row < 64)        w = Wq[row * 512 + col] * LOG2E;
        else if (row < 128)  w = Wk[(row - 64) * 512 + col];
        else                 w = Wv[(row - 128) * 512 + col];
        Wcat[idx] = f2bf(w);
    }
    if (idx < 640) {
        float bb;
        if (idx < 64)        bb = bq[idx] * LOG2E;
        else if (idx < 128)  bb = bk[idx - 64];
        else                 bb = bv[idx - 128];
        biascat[idx] = bb;
    }
}

// ---------------- transpose x [B][C][N] f32 -> xT [B][N][C] bf16 ----------------
__global__ void transpose_x(const float* __restrict__ x, u16* __restrict__ xT) {
    __shared__ float tile[32][33];
    int n0 = blockIdx.x * 32, c0 = blockIdx.y * 32, b = blockIdx.z;
    int tx = threadIdx.x & 31, ty = threadIdx.x >> 5;       // ty 0..7
    const float* xb = x + (size_t)b * C_ * N_;
#pragma unroll
    for (int r = 0; r < 4; r++) {
        int c = ty * 4 + r;
        tile[c][tx] = xb[(size_t)(c0 + c) * N_ + n0 + tx];
    }
    __syncthreads();
    u16* xTb = xT + (size_t)b * N_ * C_;
#pragma unroll
    for (int r = 0; r < 4; r++) {
        int n = ty * 4 + r;
        xTb[(size_t)(n0 + n) * C_ + c0 + tx] = f2bf(tile[tx][n]);
    }
}

// ---------------- projection GEMM: Y[640][4096] = Wcat x X_b^T, per batch --------
__global__ __launch_bounds__(256) void proj_gemm(const u16* __restrict__ Wcat,
                                                 const float* __restrict__ biascat,
                                                 const u16* __restrict__ xT,
                                                 u16* __restrict__ qT, u16* __restrict__ kT,
                                                 u16* __restrict__ v) {
    int b = blockIdx.z;
    int m0 = blockIdx.y * 64;
    int wave = threadIdx.x >> 6, lane = threadIdx.x & 63;
    int n0 = blockIdx.x * 256 + wave * 64;
    int lr = lane & 15, lc = lane >> 4;
    const u16* xTb = xT + (size_t)b * N_ * C_;

    f32x4 acc[4][4] = {};   // [ma][na]
    short8 aF[4], bF[4], aFn[4], bFn[4];
#pragma unroll
    for (int ma = 0; ma < 4; ma++)
        aF[ma] = *reinterpret_cast<const short8*>(&Wcat[(size_t)(m0 + ma * 16 + lr) * 512 + lc * 8]);
#pragma unroll
    for (int na = 0; na < 4; na++)
        bF[na] = *reinterpret_cast<const short8*>(&xTb[(size_t)(n0 + na * 16 + lr) * 512 + lc * 8]);

    for (int k0 = 0; k0 < 512; k0 += 32) {
        if (k0 < 480) {
            int kn = k0 + 32;
#pragma unroll
            for (int ma = 0; ma < 4; ma++)
                aFn[ma] = *reinterpret_cast<const short8*>(&Wcat[(size_t)(m0 + ma * 16 + lr) * 512 + kn + lc * 8]);
#pragma unroll
            for (int na = 0; na < 4; na++)
                bFn[na] = *reinterpret_cast<const short8*>(&xTb[(size_t)(n0 + na * 16 + lr) * 512 + kn + lc * 8]);
        }
#pragma unroll
        for (int ma = 0; ma < 4; ma++)
#pragma unroll
            for (int na = 0; na < 4; na++)
                acc[ma][na] = MFMA16(aF[ma], bF[na], acc[ma][na]);
#pragma unroll
        for (int t = 0; t < 4; t++) { aF[t] = aFn[t]; bF[t] = bFn[t]; }
    }
#pragma unroll
    for (int ma = 0; ma < 4; ma++) {
#pragma unroll
        for (int r = 0; r < 4; r++) {
            int m = m0 + ma * 16 + lc * 4 + r;
            float bias = biascat[m];
#pragma unroll
            for (int na = 0; na < 4; na++) {
                int n = n0 + na * 16 + lr;
                u16 hv = f2bf(acc[ma][na][r] + bias);
                if (m < 64)
                    qT[((size_t)b * N_ + n) * D_ + m] = hv;
                else if (m < 128)
                    kT[((size_t)b * N_ + n) * D_ + (m - 64)] = hv;
                else
                    v[((size_t)b * C_ + (m - 128)) * (size_t)N_ + n] = hv;
            }
        }
    }
}

// ---------------- fused attention, one pass, no max-subtraction ----------------
// Block: 64 i-rows; 8 waves; wave w owns c-slice [w*64,+64) and ALL 64 i.
// Per 128-j tile: (A) issue 16 V dwordx4 loads + sched_barrier pin, (C) S phase =
// swapped mfma(K,Q) + exp2 + pack -> swizzled LDS, (D) lgkmcnt(0)+raw s_barrier
// (NO vmcnt drain -> V stays in flight), (E) PV: issue K(jt+1) loads, then
// setprio-wrapped MFMA cluster consuming prefetched V.
__global__ __launch_bounds__(512) void attn(const u16* __restrict__ qT, const u16* __restrict__ kT,
                                            const u16* __restrict__ v, const float* __restrict__ x,
                                            const float* __restrict__ gamma_p, float* __restrict__ out) {
    int w = blockIdx.x;                 // [0,256)
    int xcd = w & 7, slot = w >> 3;     // slot in [0,32)
    int b = xcd >> 1;
    int i0 = (slot * 2 + (xcd & 1)) * 64;

    int wv = threadIdx.x >> 6, lane = threadIdx.x & 63;
    int lr = lane & 15, lc = lane >> 4;

    __shared__ u16 P_lds[2][64 * 128];  // 2 x 16KB, swizzled: byte = i*256 + (jb ^ ((i&7)<<4))
    __shared__ float s_l[64][8];        // per-wave partial row sums

    const u16* qTb = qT + (size_t)b * N_ * D_;
    const u16* kTb = kT + (size_t)b * N_ * D_;
    const u16* vb  = v  + (size_t)b * C_ * N_;

    // Q fragments: 64 i x 64 d, held all kernel (B-operand: row=lr, k-chunk=lc*8)
    short8 qf[4][2];
#pragma unroll
    for (int mt = 0; mt < 4; mt++)
#pragma unroll
        for (int kd = 0; kd < 2; kd++)
            qf[mt][kd] = *reinterpret_cast<const short8*>(
                &qTb[(size_t)(i0 + mt * 16 + lr) * D_ + kd * 32 + lc * 8]);

    f32x4 acc[4][4] = {};               // [mt][ct]: O slice 64 i x 64 c (unnormalized)
    float lsum[4] = {0.f, 0.f, 0.f, 0.f};

    // prefetch K for jt=0: wave's 16-j slice
    short8 kf0, kf1, kf0n, kf1n;
    {
        const u16* kp = kTb + (size_t)(wv * 16 + lr) * D_;
        kf0 = *reinterpret_cast<const short8*>(kp + lc * 8);
        kf1 = *reinterpret_cast<const short8*>(kp + 32 + lc * 8);
    }

    for (int jt = 0; jt < 32; jt++) {
        char* pb = reinterpret_cast<char*>(P_lds[jt & 1]);

        // ---- (A) V prefetch for THIS jt, pinned so the scheduler can't sink it ----
        short8 vf[16];
#pragma unroll
        for (int kt = 0; kt < 4; kt++)
#pragma unroll
            for (int ct = 0; ct < 4; ct++)
                vf[kt * 4 + ct] = *reinterpret_cast<const short8*>(
                    &vb[(size_t)(wv * 64 + ct * 16 + lr) * N_ + jt * 128 + kt * 32 + lc * 8]);
        __builtin_amdgcn_sched_barrier(0);   // pin: V loads must be issued here

        // ---- (C) S phase: swapped mfma(K,Q): lane holds S'[i=mt*16+lr][j=wv*16+lc*4+r] ----
#pragma unroll
        for (int mt = 0; mt < 4; mt++) {
            f32x4 s = {};
            s = MFMA16(kf0, qf[mt][0], s);
            s = MFMA16(kf1, qf[mt][1], s);
            s16x4 pk;
            float ps = 0.f;
#pragma unroll
            for (int r = 0; r < 4; r++) {
                float p = __builtin_amdgcn_exp2f(s[r]);   // exp(q.k): log2e folded into Wq
                ps += p;
                pk[r] = (short)f2bf(p);
            }
            lsum[mt] += ps;
            int i = mt * 16 + lr;
            int byte_off = i * 256 + ((wv * 32 + lc * 8) ^ ((i & 7) << 4));
            *reinterpret_cast<s16x4*>(pb + byte_off) = pk;
        }

        // ---- (D) barrier WITHOUT vmcnt drain: drain own LDS writes, then raw barrier ----
        asm volatile("s_waitcnt lgkmcnt(0)" ::: "memory");
        __builtin_amdgcn_s_barrier();
        __builtin_amdgcn_sched_barrier(0);

        // ---- (E) PV phase: first issue K prefetch for jt+1 (window = whole PV) ----
        if (jt < 31) {
            const u16* kp = kTb + (size_t)((jt + 1) * 128 + wv * 16 + lr) * D_;
            kf0n = *reinterpret_cast<const short8*>(kp + lc * 8);
            kf1n = *reinterpret_cast<const short8*>(kp + 32 + lc * 8);
        }
        __builtin_amdgcn_sched_barrier(0);   // pin: K loads issued before MFMA cluster

        __builtin_amdgcn_s_setprio(1);
#pragma unroll
        for (int kt = 0; kt < 4; kt++) {
            short8 pf[4];
#pragma unroll
            for (int mt = 0; mt < 4; mt++) {
                int i = mt * 16 + lr;
                int byte_off = i * 256 + (((kt * 64) + lc * 16) ^ ((i & 7) << 4));
                pf[mt] = *reinterpret_cast<const short8*>(pb + byte_off);
            }
#pragma unroll
            for (int ct = 0; ct < 4; ct++)
#pragma unroll
                for (int mt = 0; mt < 4; mt++)
                    acc[mt][ct] = MFMA16(pf[mt], vf[kt * 4 + ct], acc[mt][ct]);
        }
        __builtin_amdgcn_s_setprio(0);
        kf0 = kf0n; kf1 = kf1n;
    }

    // ---- row-sum reduce: lane has lsum[mt] for i = mt*16+lr over its (wv, lc) j-set ----
#pragma unroll
    for (int mt = 0; mt < 4; mt++) {
        float l_ = lsum[mt];
        l_ += __shfl_xor(l_, 16);
        l_ += __shfl_xor(l_, 32);
        if (lc == 0) s_l[mt * 16 + lr][wv] = l_;
    }
    __syncthreads();

    // ---- epilogue: out = gamma * (O / l) + x ----
    float g = gamma_p[0];
    const float* xb = x + (size_t)b * C_ * N_;
    float* ob = out + (size_t)b * C_ * N_;
#pragma unroll
    for (int mt = 0; mt < 4; mt++) {
        float linv[4];
#pragma unroll
        for (int r = 0; r < 4; r++) {
            int i = mt * 16 + lc * 4 + r;
            float4 l0 = *reinterpret_cast<const float4*>(&s_l[i][0]);
            float4 l1 = *reinterpret_cast<const float4*>(&s_l[i][4]);
            linv[r] = 1.0f / (l0.x + l0.y + l0.z + l0.w + l1.x + l1.y + l1.z + l1.w);
        }
#pragma unroll
        for (int ct = 0; ct < 4; ct++) {
            int c = wv * 64 + ct * 16 + lr;
            size_t off = (size_t)c * N_ + i0 + mt * 16 + lc * 4;
            float4 xv = *reinterpret_cast<const float4*>(&xb[off]);
            float4 ov;
            ov.x = g * acc[mt][ct][0] * linv[0] + xv.x;
            ov.y = g * acc[mt][ct][1] * linv[1] + xv.y;
            ov.z = g * acc[mt][ct][2] * linv[2] + xv.z;
            ov.w = g * acc[mt][ct][3] * linv[3] + xv.w;
            *reinterpret_cast<float4*>(&ob[off]) = ov;
        }
    }
}

extern "C" void kernel_launch(void* const* d_in, const int* in_sizes, int n_in,
                              void* d_out, int out_size, void* d_ws, size_t ws_size,
                              hipStream_t stream) {
    const float* x     = (const float*)d_in[0];
    const float* Wq    = (const float*)d_in[1];
    const float* bq    = (const float*)d_in[2];
    const float* Wk    = (const float*)d_in[3];
    const float* bk    = (const float*)d_in[4];
    const float* Wv    = (const float*)d_in[5];
    const float* bv    = (const float*)d_in[6];
    const float* gamma = (const float*)d_in[7];
    float* out = (float*)d_out;

    char* ws = (char*)d_ws;
    // layout (bytes): xT 16MB | Wcat 640KB | biascat 2.5KB | qT 2MB | kT 2MB | v 16MB
    u16*   xT      = (u16*)ws;
    u16*   Wcat    = (u16*)(ws + (size_t)16777216);
    float* biascat = (float*)(ws + (size_t)16777216 + 655360);
    u16*   qT      = (u16*)(ws + (size_t)16777216 + 655360 + 4096);
    u16*   kT      = qT + (size_t)B_ * N_ * D_;
    u16*   v       = kT + (size_t)B_ * N_ * D_;

    prep_w<<<1280, 256, 0, stream>>>(Wq, bq, Wk, bk, Wv, bv, Wcat, biascat);
    transpose_x<<<dim3(N_ / 32, C_ / 32, B_), 256, 0, stream>>>(x, xT);
    proj_gemm<<<dim3(N_ / 256, 640 / 64, B_), 256, 0, stream>>>(Wcat, biascat, xT, qT, kT, v);
    attn<<<256, 512, 0, stream>>>(qT, kT, v, x, gamma, out);
}